// Round 1
// 262.593 us; speedup vs baseline: 1.0056x; 1.0056x over previous
//
#include <hip/hip_runtime.h>
#include <hip/hip_fp16.h>

typedef __attribute__((ext_vector_type(8))) _Float16 half8;
typedef __attribute__((ext_vector_type(4))) float f32x4;
typedef unsigned int u32;
typedef unsigned short u16;
typedef unsigned long long u64;

#define ELL_PAD 64

// ---------- K1: zero degree counters + zero phantom pad rows of xh + pack W ----------
// Pack layout (B-fragment order for mfma_f32_16x16x32_f16):
// elem j of (layer,ntile,kstep,lane) = W[k=kstep*32+(lane>>4)*8+j][n=ntile*16+(lane&15)]

__global__ __launch_bounds__(256) void initpack(int* __restrict__ deg_out,
                                                int* __restrict__ deg_in,
                                                u32* __restrict__ xz0,
                                                u32* __restrict__ xz1,
                                                const float* __restrict__ Ws,
                                                _Float16* __restrict__ Whi,
                                                _Float16* __restrict__ Wlo,
                                                int N, int padU32, int zb, int packTotal) {
  int b = blockIdx.x;
  if (b < zb) {
    int i = b * 256 + threadIdx.x;
    if (i < N) { deg_out[i] = 0; deg_in[i] = 0; }
    if (b == 0) {
      // zero phantom rows [N, N+16) of both ping buffers (gather pad target)
      for (int j = threadIdx.x; j < padU32; j += 256) { xz0[j] = 0; xz1[j] = 0; }
    }
    return;
  }
  int i = (b - zb) * 256 + threadIdx.x;
  if (i < packTotal) {
    int lane  = i & 63;
    int kstep = (i >> 6) & 3;
    int ntile = (i >> 8) & 7;
    int layer = i >> 11;
    int nn = ntile * 16 + (lane & 15);
    int k0 = kstep * 32 + (lane >> 4) * 8;
    const float* W = Ws + (size_t)layer * 128 * 128;
    size_t base = (size_t)i * 8;
    for (int j = 0; j < 8; j++) {
      float v = W[(k0 + j) * 128 + nn];
      _Float16 hi = (_Float16)v;
      Whi[base + j] = hi;
      Wlo[base + j] = (_Float16)(v - (float)hi);   // exact residual
    }
  }
}

// ---------- K2: single edge pass — degree count + ELL placement via global atomics ----------
// Counters are 400 KB total -> L2-resident; 1.28M atomics at avg 12.8/address is
// contention-free. Replaces hist2+prep+place (~150 MB of psrc/pdst round-trips).

__global__ __launch_bounds__(256) void build(const int* __restrict__ esrc,
                                             const int* __restrict__ edst,
                                             int* __restrict__ deg_out,
                                             int* __restrict__ deg_in,
                                             u16* __restrict__ ell, int E) {
  int i = blockIdx.x * 256 + threadIdx.x;
  if (i >= E) return;
  int s = esrc[i];
  int d = edst[i];
  atomicAdd(&deg_out[s], 1);
  int p = atomicAdd(&deg_in[d], 1);
  if (p < ELL_PAD) ell[(u32)d * ELL_PAD + (u32)p] = (u16)s;
}

// ---------- K3: xh[i,:] = fp16( x[i,:] * rsqrt(max(deg_out,1)) ) + pad ELL rows to 4 ----------

__global__ __launch_bounds__(256) void xscale(const float* __restrict__ x,
                                              const int* __restrict__ deg_out,
                                              const int* __restrict__ deg_in,
                                              __half2* __restrict__ xh,
                                              u16* __restrict__ ell,
                                              int N, int n64) {
  int gid = blockIdx.x * 256 + threadIdx.x;
  if (gid >= n64) return;
  int row = gid >> 6;
  int d = deg_out[row]; if (d < 1) d = 1;
  float s = rsqrtf((float)d);
  float2 v = ((const float2*)x)[gid];
  xh[gid] = __floats2half2_rn(v.x * s, v.y * s);
  if ((gid & 63) == 0) {
    // pad this row's ELL up to a multiple of 4 with the phantom zero-row index N
    int c = deg_in[row];
    int l = c > ELL_PAD ? ELL_PAD : c;
    int t = (l + 3) & ~3;
    u16* ep = ell + (u32)row * ELL_PAD;
    for (int q = l; q < t; q++) ep[q] = (u16)N;
  }
}

// ---------- K4: fused layer — 16-row tile, 8 waves ----------
// Gather restructured: 16 lanes per edge, dwordx4 (16 B/lane) loads. One wave-load
// covers 4 edges' full 256 B rows -> 4x fewer VMEM instructions/waitcnts than the
// dword-per-edge version at identical cacheline MLP. lane = (grp:2, sub:4):
// sub selects halves [sub*8, sub*8+8), grp selects edge within a 4-group. ELL rows
// are padded to x4 with the phantom zero row, so there are no scalar tails.
// u32 byte offsets -> SADDR-form global_load_dwordx4.

__global__ __launch_bounds__(512) void layer16(const _Float16* __restrict__ xh,
                                               const int* __restrict__ deg_in,
                                               const u16* __restrict__ ell,
                                               const _Float16* __restrict__ Whi,
                                               const _Float16* __restrict__ Wlo,
                                               const float* __restrict__ bias,
                                               const int* __restrict__ deg_out,
                                               __half* __restrict__ out16,
                                               float* __restrict__ out32, int n) {
  __shared__ _Float16 As[16 * 136];   // 4.25 KB; stride 136 halves
  const int wave = threadIdx.x >> 6;
  const int lane = threadIdx.x & 63;
  const int sub  = lane & 15;
  const int grp  = lane >> 4;
  const int sh   = grp << 4;          // u64 shift to extract this grp's edge index
  const u32 sub16 = (u32)sub * 16u;   // byte offset within a 256 B row
  const int rowBase = blockIdx.x * 16;
  const char* __restrict__ xb = (const char*)xh;

  // ---- gather phase: 2 rows per wave
  {
    int r0 = rowBase + wave * 2, r1 = r0 + 1;
    int d0 = (r0 < n) ? deg_in[r0] : 0;
    int d1 = (r1 < n) ? deg_in[r1] : 0;
    int l0 = d0 > ELL_PAD ? ELL_PAD : d0;
    int l1 = d1 > ELL_PAD ? ELL_PAD : d1;
    int t0 = (l0 + 3) & ~3;           // padded trip counts (multiple of 4)
    int t1 = (l1 + 3) & ~3;
    const u16* ep0 = ell + (u32)(r0 < n ? r0 : 0) * ELL_PAD;
    const u16* ep1 = ell + (u32)(r1 < n ? r1 : 0) * ELL_PAD;

    float a0[8] = {0.f, 0.f, 0.f, 0.f, 0.f, 0.f, 0.f, 0.f};
    float a1[8] = {0.f, 0.f, 0.f, 0.f, 0.f, 0.f, 0.f, 0.f};

    int m = t0 < t1 ? t0 : t1;
    int e = 0;
    // joint x8: 4 dwordx4 gathers in flight (32 cachelines)
    for (; e + 8 <= m; e += 8) {
      u64 wa0 = *(const u64*)&ep0[e];
      u64 wa1 = *(const u64*)&ep0[e + 4];
      u64 wb0 = *(const u64*)&ep1[e];
      u64 wb1 = *(const u64*)&ep1[e + 4];
      u32 ia0 = ((u32)(wa0 >> sh) & 0xFFFFu) * 256u + sub16;
      u32 ia1 = ((u32)(wa1 >> sh) & 0xFFFFu) * 256u + sub16;
      u32 ib0 = ((u32)(wb0 >> sh) & 0xFFFFu) * 256u + sub16;
      u32 ib1 = ((u32)(wb1 >> sh) & 0xFFFFu) * 256u + sub16;
      half8 va0 = *(const half8*)(xb + ia0);
      half8 va1 = *(const half8*)(xb + ia1);
      half8 vb0 = *(const half8*)(xb + ib0);
      half8 vb1 = *(const half8*)(xb + ib1);
#pragma unroll
      for (int j = 0; j < 8; j++) {
        a0[j] += (float)va0[j] + (float)va1[j];
        a1[j] += (float)vb0[j] + (float)vb1[j];
      }
    }
    // joint x4 remainder
    for (; e < m; e += 4) {
      u64 wa = *(const u64*)&ep0[e];
      u64 wb = *(const u64*)&ep1[e];
      u32 ia = ((u32)(wa >> sh) & 0xFFFFu) * 256u + sub16;
      u32 ib = ((u32)(wb >> sh) & 0xFFFFu) * 256u + sub16;
      half8 va = *(const half8*)(xb + ia);
      half8 vb = *(const half8*)(xb + ib);
#pragma unroll
      for (int j = 0; j < 8; j++) { a0[j] += (float)va[j]; a1[j] += (float)vb[j]; }
    }
    // per-row x4 remainders
    for (int ea = m; ea < t0; ea += 4) {
      u64 wa = *(const u64*)&ep0[ea];
      u32 ia = ((u32)(wa >> sh) & 0xFFFFu) * 256u + sub16;
      half8 va = *(const half8*)(xb + ia);
#pragma unroll
      for (int j = 0; j < 8; j++) a0[j] += (float)va[j];
    }
    for (int eb = m; eb < t1; eb += 4) {
      u64 wb = *(const u64*)&ep1[eb];
      u32 ib = ((u32)(wb >> sh) & 0xFFFFu) * 256u + sub16;
      half8 vb = *(const half8*)(xb + ib);
#pragma unroll
      for (int j = 0; j < 8; j++) a1[j] += (float)vb[j];
    }

    // combine the 4 grp partials (lane bits 4,5) -> all lanes hold totals
#pragma unroll
    for (int j = 0; j < 8; j++) {
      a0[j] += __shfl_xor(a0[j], 16, 64);
      a0[j] += __shfl_xor(a0[j], 32, 64);
      a1[j] += __shfl_xor(a1[j], 16, 64);
      a1[j] += __shfl_xor(a1[j], 32, 64);
    }

    float si0 = rsqrtf((float)(d0 < 1 ? 1 : d0));
    float si1 = rsqrtf((float)(d1 < 1 ? 1 : d1));
    if (grp == 0) {
      half8 h0, h1;
#pragma unroll
      for (int j = 0; j < 8; j++) {
        h0[j] = (_Float16)(a0[j] * si0);
        h1[j] = (_Float16)(a1[j] * si1);
      }
      *(half8*)&As[(wave * 2 + 0) * 136 + sub * 8] = h0;
      *(half8*)&As[(wave * 2 + 1) * 136 + sub * 8] = h1;
    }
  }
  __syncthreads();

  // ---- GEMM phase: wave w computes C[0:16, w*16:(w+1)*16]
  f32x4 acc = (f32x4){0.f, 0.f, 0.f, 0.f};
#pragma unroll
  for (int ks = 0; ks < 4; ks++) {
    half8 a  = *(const half8*)&As[(size_t)sub * 136 + ks * 32 + grp * 8];
    half8 bh = *(const half8*)&Whi[((wave * 4 + ks) * 64 + lane) * 8];
    half8 bl = *(const half8*)&Wlo[((wave * 4 + ks) * 64 + lane) * 8];
    acc = __builtin_amdgcn_mfma_f32_16x16x32_f16(a, bh, acc, 0, 0, 0);
    acc = __builtin_amdgcn_mfma_f32_16x16x32_f16(a, bl, acc, 0, 0, 0);
  }

  // C/D: col = lane&15 (+wave*16), row = grp*4 + reg  [m89-verified mapping]
  const int r0c = rowBase + grp * 4;
  const int col = wave * 16 + sub;
  const float bv = bias[col];
#pragma unroll
  for (int r = 0; r < 4; r++) {
    int row = r0c + r;
    if (row < n) {
      float v = fmaxf(acc[r] + bv, 0.f);
      if (out16) {
        int d = deg_out[row]; if (d < 1) d = 1;
        out16[(size_t)row * 128 + col] = __float2half(v * rsqrtf((float)d));
      } else {
        out32[(size_t)row * 128 + col] = v;
      }
    }
  }
}

// ---------- launch ----------

extern "C" void kernel_launch(void* const* d_in, const int* in_sizes, int n_in,
                              void* d_out, int out_size, void* d_ws, size_t ws_size,
                              hipStream_t stream) {
  const float* x   = (const float*)d_in[0];
  const float* Ws  = (const float*)d_in[1];
  const float* bs  = (const float*)d_in[2];
  const int* esrc  = (const int*)d_in[3];
  const int* edst  = (const int*)d_in[4];

  const int D = 128;
  const int N = in_sizes[0] / D;
  const int E = in_sizes[3];
  const int L = in_sizes[1] / (D * D);
  const int Npad = ((N + 15) / 16) * 16;

  // workspace layout, 256B-aligned chunks (no aliasing)
  char* base = (char*)d_ws;
  size_t off = 0;
  auto alloc = [&](size_t bytes) {
    char* p = base + off;
    off = (off + bytes + 255) & ~(size_t)255;
    return p;
  };
  int*      deg_out = (int*)alloc((size_t)N * 4);
  int*      deg_in  = (int*)alloc((size_t)N * 4);
  u16*      ell     = (u16*)alloc((size_t)N * ELL_PAD * 2);
  _Float16* Whi     = (_Float16*)alloc((size_t)L * 16384 * 2);
  _Float16* Wlo     = (_Float16*)alloc((size_t)L * 16384 * 2);
  _Float16* xh0     = (_Float16*)alloc((size_t)(Npad + 16) * 128 * 2);
  _Float16* xh1     = (_Float16*)alloc((size_t)(Npad + 16) * 128 * 2);

  const int zb = (N + 255) / 256;
  const int packTotal = L * 2048;
  const int packB = (packTotal + 255) / 256;
  const int padU32 = 16 * 64;   // 16 phantom rows x 128 halves = 1024 u32 per buffer

  initpack<<<dim3(zb + packB), dim3(256), 0, stream>>>(
      deg_out, deg_in,
      (u32*)(xh0 + (size_t)N * 128), (u32*)(xh1 + (size_t)N * 128),
      Ws, Whi, Wlo, N, padU32, zb, packTotal);
  build<<<dim3((E + 255) / 256), dim3(256), 0, stream>>>(
      esrc, edst, deg_out, deg_in, ell, E);
  xscale<<<dim3((N * 64 + 255) / 256), dim3(256), 0, stream>>>(
      x, deg_out, deg_in, (__half2*)xh0, ell, N, N * 64);

  float* outf = (float*)d_out;
  _Float16* ping[2] = {xh0, xh1};
  const dim3 lgrid(Npad / 16), lblk(512);

  for (int l = 0; l < L; l++) {
    bool last = (l == L - 1);
    layer16<<<lgrid, lblk, 0, stream>>>(
        (const _Float16*)ping[l & 1], deg_in, ell,
        Whi + (size_t)l * 16384, Wlo + (size_t)l * 16384,
        bs + (size_t)l * D, deg_out,
        last ? nullptr : (__half*)ping[(l + 1) & 1],
        last ? outf : nullptr, N);
  }
}

// Round 2
// 250.775 us; speedup vs baseline: 1.0530x; 1.0471x over previous
//
#include <hip/hip_runtime.h>
#include <hip/hip_fp16.h>

typedef __attribute__((ext_vector_type(8))) _Float16 half8;
typedef __attribute__((ext_vector_type(4))) float f32x4;
typedef unsigned int u32;
typedef unsigned short u16;
typedef unsigned long long u64;

#define ELL_PAD 64
#define BKT 128          // nodes per dst-bucket (partb LDS slice = 128*64*2B = 16 KB)
#define BKT_SH 7
#define EPB 2048         // edges per parta block (LDS stage = 8 KB)
#define NAMAX 512        // max parta blocks supported by partb's LDS run tables

// ---------- K1: zero deg_out + zero phantom pad rows of xh + pack W ----------
// Pack layout (B-fragment order for mfma_f32_16x16x32_f16):
// elem j of (layer,ntile,kstep,lane) = W[k=kstep*32+(lane>>4)*8+j][n=ntile*16+(lane&15)]

__global__ __launch_bounds__(256) void initpack(int* __restrict__ deg_out,
                                                u32* __restrict__ xz0,
                                                u32* __restrict__ xz1,
                                                const float* __restrict__ Ws,
                                                _Float16* __restrict__ Whi,
                                                _Float16* __restrict__ Wlo,
                                                int N, int padU32, int zb, int packTotal) {
  int b = blockIdx.x;
  if (b < zb) {
    int i = b * 256 + threadIdx.x;
    if (i < N) deg_out[i] = 0;
    if (b == 0) {
      // zero phantom rows [N, N+16) of both ping buffers (gather pad target)
      for (int j = threadIdx.x; j < padU32; j += 256) { xz0[j] = 0; xz1[j] = 0; }
    }
    return;
  }
  int i = (b - zb) * 256 + threadIdx.x;
  if (i < packTotal) {
    int lane  = i & 63;
    int kstep = (i >> 6) & 3;
    int ntile = (i >> 8) & 7;
    int layer = i >> 11;
    int nn = ntile * 16 + (lane & 15);
    int k0 = kstep * 32 + (lane >> 4) * 8;
    const float* W = Ws + (size_t)layer * 128 * 128;
    size_t base = (size_t)i * 8;
    for (int j = 0; j < 8; j++) {
      float v = W[(k0 + j) * 128 + nn];
      _Float16 hi = (_Float16)v;
      Whi[base + j] = hi;
      Wlo[base + j] = (_Float16)(v - (float)hi);   // exact residual
    }
  }
}

// ---------- K2a: block-local counting sort of edges into dst-buckets ----------
// Each block owns EPB edges: LDS histogram over NB buckets -> exclusive prefix ->
// LDS-staged reorder -> ONE fully coalesced write of packed {src:16,dstLocal:7}
// pairs into the block's own region of `part`, plus per-(block,bucket) run table.
// No cross-block prefix needed: partb consumes runs per block. This replaces the
// scattered u16 ELL stores (64B-line write-through, 41 MB HBM) with dense writes.

__global__ __launch_bounds__(256) void parta(const int* __restrict__ esrc,
                                             const int* __restrict__ edst,
                                             int* __restrict__ deg_out,
                                             u32* __restrict__ part,
                                             u32* __restrict__ runTab,
                                             int E, int NB) {
  __shared__ u32 hist[1024];      // NB+1 <= 1024
  __shared__ u32 stage[EPB];      // 8 KB
  int a = blockIdx.x;
  int e0 = a * EPB;
  int e1 = min(E, e0 + EPB);
  int len = e1 - e0;
  for (int j = threadIdx.x; j <= NB; j += 256) hist[j] = 0;
  __syncthreads();
  // pass 1: histogram + deg_out atomics (no return value needed)
  for (int i = e0 + threadIdx.x; i < e1; i += 256) {
    int s = esrc[i];
    int d = edst[i];
    atomicAdd(&deg_out[s], 1);
    atomicAdd(&hist[d >> BKT_SH], 1u);
  }
  __syncthreads();
  if (threadIdx.x == 0) {
    u32 run = 0;
    for (int b = 0; b < NB; b++) { u32 t = hist[b]; hist[b] = run; run += t; }
  }
  __syncthreads();
  // emit run table (prefix values) BEFORE pass 2 turns hist[] into cursors
  u32* rt = runTab + (size_t)a * (NB + 1);
  for (int b = threadIdx.x; b < NB; b += 256) rt[b] = hist[b];
  if (threadIdx.x == 0) rt[NB] = (u32)len;
  __syncthreads();
  // pass 2: place into LDS staging ordered by bucket (edges are L2-hot re-reads)
  for (int i = e0 + threadIdx.x; i < e1; i += 256) {
    int s = esrc[i];
    int d = edst[i];
    u32 p = atomicAdd(&hist[d >> BKT_SH], 1u);
    stage[p] = (u32)s | ((u32)(d & (BKT - 1)) << 16);
  }
  __syncthreads();
  // pass 3: dense coalesced write of the block's region
  u32* op = part + (size_t)a * EPB;
  for (int j = threadIdx.x; j < len; j += 256) op[j] = stage[j];
}

// ---------- K2b: per-bucket ELL slice build in LDS, dense writes ----------
// Block b owns nodes [b*BKT, b*BKT+BKT). Slice pre-filled with phantom index N
// (so ELL pad slots need no separate pass and deg_in needs no pre-zero).
// Flattened run iteration + binary search keeps all 256 lanes busy and the
// part[] reads pipelined. Output: 16 KB dense ELL lines + coalesced deg_in.

__global__ __launch_bounds__(256) void partb(const u32* __restrict__ part,
                                             const u32* __restrict__ runTab,
                                             int* __restrict__ deg_in,
                                             u16* __restrict__ ell,
                                             int N, int NA, int NB) {
  __shared__ u16 slice[BKT * ELL_PAD];   // 16 KB
  __shared__ u32 cnt[BKT];
  __shared__ u32 roff[NAMAX + 1];
  __shared__ u32 rbase[NAMAX];
  int b = blockIdx.x;
  int base = b * BKT;
  int hi = min(BKT, N - base);
  if (hi <= 0) return;

  u32 nv = ((u32)N << 16) | (u32)N;      // two phantom entries
  u32* s32 = (u32*)slice;
  for (int j = threadIdx.x; j < BKT * (ELL_PAD / 2); j += 256) s32[j] = nv;
  for (int j = threadIdx.x; j < BKT; j += 256) cnt[j] = 0;
  for (int a = threadIdx.x; a < NA; a += 256) {
    u32 s = runTab[(size_t)a * (NB + 1) + b];
    u32 e = runTab[(size_t)a * (NB + 1) + b + 1];
    roff[a]  = e - s;                    // temp: run length
    rbase[a] = (u32)a * EPB + s;         // global start of run a
  }
  __syncthreads();
  if (threadIdx.x == 0) {
    u32 run = 0;
    for (int a = 0; a < NA; a++) { u32 t = roff[a]; roff[a] = run; run += t; }
    roff[NA] = run;
  }
  __syncthreads();
  int T = (int)roff[NA];
  for (int i = threadIdx.x; i < T; i += 256) {
    int lo = 0, hh = NA;                 // find run: roff[lo] <= i < roff[lo+1]
    while (hh - lo > 1) {
      int mid = (lo + hh) >> 1;
      if (roff[mid] <= (u32)i) lo = mid; else hh = mid;
    }
    u32 pair = part[(size_t)rbase[lo] + ((u32)i - roff[lo])];
    u32 dl  = pair >> 16;
    u32 src = pair & 0xFFFFu;
    u32 c = atomicAdd(&cnt[dl], 1u);
    if (c < ELL_PAD) slice[dl * ELL_PAD + c] = (u16)src;
  }
  __syncthreads();
  for (int t = threadIdx.x; t < hi; t += 256) deg_in[base + t] = (int)cnt[t];
  u32* eg = (u32*)(ell + (size_t)base * ELL_PAD);
  for (int j = threadIdx.x; j < hi * (ELL_PAD / 2); j += 256) eg[j] = s32[j];
}

// ---------- K3: xh[i,:] = fp16( x[i,:] * rsqrt(max(deg_out,1)) ) ----------

__global__ __launch_bounds__(256) void xscale(const float* __restrict__ x,
                                              const int* __restrict__ deg_out,
                                              __half2* __restrict__ xh, int n64) {
  int gid = blockIdx.x * 256 + threadIdx.x;
  if (gid >= n64) return;
  int row = gid >> 6;
  int d = deg_out[row]; if (d < 1) d = 1;
  float s = rsqrtf((float)d);
  float2 v = ((const float2*)x)[gid];
  xh[gid] = __floats2half2_rn(v.x * s, v.y * s);
}

// ---------- K4: fused layer — 16-row tile, 8 waves ----------
// 16 lanes per edge, dwordx4 (16 B/lane) gathers; ELL pad slots hold phantom
// index N whose xh row is zeroed, so there are no scalar tails.

__global__ __launch_bounds__(512) void layer16(const _Float16* __restrict__ xh,
                                               const int* __restrict__ deg_in,
                                               const u16* __restrict__ ell,
                                               const _Float16* __restrict__ Whi,
                                               const _Float16* __restrict__ Wlo,
                                               const float* __restrict__ bias,
                                               const int* __restrict__ deg_out,
                                               __half* __restrict__ out16,
                                               float* __restrict__ out32, int n) {
  __shared__ _Float16 As[16 * 136];   // 4.25 KB; stride 136 halves
  const int wave = threadIdx.x >> 6;
  const int lane = threadIdx.x & 63;
  const int sub  = lane & 15;
  const int grp  = lane >> 4;
  const int sh   = grp << 4;          // u64 shift to extract this grp's edge index
  const u32 sub16 = (u32)sub * 16u;   // byte offset within a 256 B row
  const int rowBase = blockIdx.x * 16;
  const char* __restrict__ xb = (const char*)xh;

  // ---- gather phase: 2 rows per wave
  {
    int r0 = rowBase + wave * 2, r1 = r0 + 1;
    int d0 = (r0 < n) ? deg_in[r0] : 0;
    int d1 = (r1 < n) ? deg_in[r1] : 0;
    int l0 = d0 > ELL_PAD ? ELL_PAD : d0;
    int l1 = d1 > ELL_PAD ? ELL_PAD : d1;
    int t0 = (l0 + 3) & ~3;           // padded trip counts (multiple of 4)
    int t1 = (l1 + 3) & ~3;
    const u16* ep0 = ell + (u32)(r0 < n ? r0 : 0) * ELL_PAD;
    const u16* ep1 = ell + (u32)(r1 < n ? r1 : 0) * ELL_PAD;

    float a0[8] = {0.f, 0.f, 0.f, 0.f, 0.f, 0.f, 0.f, 0.f};
    float a1[8] = {0.f, 0.f, 0.f, 0.f, 0.f, 0.f, 0.f, 0.f};

    int m = t0 < t1 ? t0 : t1;
    int e = 0;
    // joint x8: 4 dwordx4 gathers in flight (64 cachelines/wave)
    for (; e + 8 <= m; e += 8) {
      u64 wa0 = *(const u64*)&ep0[e];
      u64 wa1 = *(const u64*)&ep0[e + 4];
      u64 wb0 = *(const u64*)&ep1[e];
      u64 wb1 = *(const u64*)&ep1[e + 4];
      u32 ia0 = ((u32)(wa0 >> sh) & 0xFFFFu) * 256u + sub16;
      u32 ia1 = ((u32)(wa1 >> sh) & 0xFFFFu) * 256u + sub16;
      u32 ib0 = ((u32)(wb0 >> sh) & 0xFFFFu) * 256u + sub16;
      u32 ib1 = ((u32)(wb1 >> sh) & 0xFFFFu) * 256u + sub16;
      half8 va0 = *(const half8*)(xb + ia0);
      half8 va1 = *(const half8*)(xb + ia1);
      half8 vb0 = *(const half8*)(xb + ib0);
      half8 vb1 = *(const half8*)(xb + ib1);
#pragma unroll
      for (int j = 0; j < 8; j++) {
        a0[j] += (float)va0[j] + (float)va1[j];
        a1[j] += (float)vb0[j] + (float)vb1[j];
      }
    }
    // joint x4 remainder
    for (; e < m; e += 4) {
      u64 wa = *(const u64*)&ep0[e];
      u64 wb = *(const u64*)&ep1[e];
      u32 ia = ((u32)(wa >> sh) & 0xFFFFu) * 256u + sub16;
      u32 ib = ((u32)(wb >> sh) & 0xFFFFu) * 256u + sub16;
      half8 va = *(const half8*)(xb + ia);
      half8 vb = *(const half8*)(xb + ib);
#pragma unroll
      for (int j = 0; j < 8; j++) { a0[j] += (float)va[j]; a1[j] += (float)vb[j]; }
    }
    // per-row x4 remainders
    for (int ea = m; ea < t0; ea += 4) {
      u64 wa = *(const u64*)&ep0[ea];
      u32 ia = ((u32)(wa >> sh) & 0xFFFFu) * 256u + sub16;
      half8 va = *(const half8*)(xb + ia);
#pragma unroll
      for (int j = 0; j < 8; j++) a0[j] += (float)va[j];
    }
    for (int eb = m; eb < t1; eb += 4) {
      u64 wb = *(const u64*)&ep1[eb];
      u32 ib = ((u32)(wb >> sh) & 0xFFFFu) * 256u + sub16;
      half8 vb = *(const half8*)(xb + ib);
#pragma unroll
      for (int j = 0; j < 8; j++) a1[j] += (float)vb[j];
    }

    // combine the 4 grp partials (lane bits 4,5) -> all lanes hold totals
#pragma unroll
    for (int j = 0; j < 8; j++) {
      a0[j] += __shfl_xor(a0[j], 16, 64);
      a0[j] += __shfl_xor(a0[j], 32, 64);
      a1[j] += __shfl_xor(a1[j], 16, 64);
      a1[j] += __shfl_xor(a1[j], 32, 64);
    }

    float si0 = rsqrtf((float)(d0 < 1 ? 1 : d0));
    float si1 = rsqrtf((float)(d1 < 1 ? 1 : d1));
    if (grp == 0) {
      half8 h0, h1;
#pragma unroll
      for (int j = 0; j < 8; j++) {
        h0[j] = (_Float16)(a0[j] * si0);
        h1[j] = (_Float16)(a1[j] * si1);
      }
      *(half8*)&As[(wave * 2 + 0) * 136 + sub * 8] = h0;
      *(half8*)&As[(wave * 2 + 1) * 136 + sub * 8] = h1;
    }
  }
  __syncthreads();

  // ---- GEMM phase: wave w computes C[0:16, w*16:(w+1)*16]
  f32x4 acc = (f32x4){0.f, 0.f, 0.f, 0.f};
#pragma unroll
  for (int ks = 0; ks < 4; ks++) {
    half8 a  = *(const half8*)&As[(size_t)sub * 136 + ks * 32 + grp * 8];
    half8 bh = *(const half8*)&Whi[((wave * 4 + ks) * 64 + lane) * 8];
    half8 bl = *(const half8*)&Wlo[((wave * 4 + ks) * 64 + lane) * 8];
    acc = __builtin_amdgcn_mfma_f32_16x16x32_f16(a, bh, acc, 0, 0, 0);
    acc = __builtin_amdgcn_mfma_f32_16x16x32_f16(a, bl, acc, 0, 0, 0);
  }

  // C/D: col = lane&15 (+wave*16), row = grp*4 + reg  [m89-verified mapping]
  const int r0c = rowBase + grp * 4;
  const int col = wave * 16 + sub;
  const float bv = bias[col];
#pragma unroll
  for (int r = 0; r < 4; r++) {
    int row = r0c + r;
    if (row < n) {
      float v = fmaxf(acc[r] + bv, 0.f);
      if (out16) {
        int d = deg_out[row]; if (d < 1) d = 1;
        out16[(size_t)row * 128 + col] = __float2half(v * rsqrtf((float)d));
      } else {
        out32[(size_t)row * 128 + col] = v;
      }
    }
  }
}

// ---------- launch ----------

extern "C" void kernel_launch(void* const* d_in, const int* in_sizes, int n_in,
                              void* d_out, int out_size, void* d_ws, size_t ws_size,
                              hipStream_t stream) {
  const float* x   = (const float*)d_in[0];
  const float* Ws  = (const float*)d_in[1];
  const float* bs  = (const float*)d_in[2];
  const int* esrc  = (const int*)d_in[3];
  const int* edst  = (const int*)d_in[4];

  const int D = 128;
  const int N = in_sizes[0] / D;
  const int E = in_sizes[3];
  const int L = in_sizes[1] / (D * D);
  const int Npad = ((N + 15) / 16) * 16;
  const int NA = (E + EPB - 1) / EPB;        // parta blocks (313 for E=640K)
  const int NB = (N + BKT - 1) / BKT;        // buckets (391 for N=50K)

  // workspace layout, 256B-aligned chunks (no aliasing)
  char* base = (char*)d_ws;
  size_t off = 0;
  auto alloc = [&](size_t bytes) {
    char* p = base + off;
    off = (off + bytes + 255) & ~(size_t)255;
    return p;
  };
  int*      deg_out = (int*)alloc((size_t)N * 4);
  int*      deg_in  = (int*)alloc((size_t)N * 4);
  u16*      ell     = (u16*)alloc((size_t)N * ELL_PAD * 2);
  _Float16* Whi     = (_Float16*)alloc((size_t)L * 16384 * 2);
  _Float16* Wlo     = (_Float16*)alloc((size_t)L * 16384 * 2);
  _Float16* xh0     = (_Float16*)alloc((size_t)(Npad + 16) * 128 * 2);
  _Float16* xh1     = (_Float16*)alloc((size_t)(Npad + 16) * 128 * 2);
  u32*      part    = (u32*)alloc((size_t)NA * EPB * 4);
  u32*      runTab  = (u32*)alloc((size_t)NA * (NB + 1) * 4);

  const int zb = (N + 255) / 256;
  const int packTotal = L * 2048;
  const int packB = (packTotal + 255) / 256;
  const int padU32 = 16 * 64;   // 16 phantom rows x 128 halves = 1024 u32 per buffer

  initpack<<<dim3(zb + packB), dim3(256), 0, stream>>>(
      deg_out,
      (u32*)(xh0 + (size_t)N * 128), (u32*)(xh1 + (size_t)N * 128),
      Ws, Whi, Wlo, N, padU32, zb, packTotal);
  parta<<<dim3(NA), dim3(256), 0, stream>>>(
      esrc, edst, deg_out, part, runTab, E, NB);
  partb<<<dim3(NB), dim3(256), 0, stream>>>(
      part, runTab, deg_in, ell, N, NA, NB);
  xscale<<<dim3((N * 64 + 255) / 256), dim3(256), 0, stream>>>(
      x, deg_out, (__half2*)xh0, N * 64);

  float* outf = (float*)d_out;
  _Float16* ping[2] = {xh0, xh1};
  const dim3 lgrid(Npad / 16), lblk(512);

  for (int l = 0; l < L; l++) {
    bool last = (l == L - 1);
    layer16<<<lgrid, lblk, 0, stream>>>(
        (const _Float16*)ping[l & 1], deg_in, ell,
        Whi + (size_t)l * 16384, Wlo + (size_t)l * 16384,
        bs + (size_t)l * D, deg_out,
        last ? nullptr : (__half*)ping[(l + 1) & 1],
        last ? outf : nullptr, N);
  }
}